// Round 5
// baseline (260.639 us; speedup 1.0000x reference)
//
#include <hip/hip_runtime.h>

typedef unsigned short u16;
typedef unsigned int u32;
typedef __attribute__((ext_vector_type(8))) short short8;
typedef __attribute__((ext_vector_type(4))) float f32x4;

#define NN 20000
#define EE 640000
#define SCAN_BLOCKS 80   // 80*256 = 20480 >= NN

__device__ inline u16 f2bf(float f) {
    u32 x = __float_as_uint(f);
    return (u16)((x + 0x7FFFu + ((x >> 16) & 1u)) >> 16);
}
__device__ inline float lo16(u32 w) { return __uint_as_float(w << 16); }
__device__ inline float hi16(u32 w) { return __uint_as_float(w & 0xFFFF0000u); }
__device__ inline u32 packbf(float a, float b) { return ((u32)f2bf(b) << 16) | (u32)f2bf(a); }

// ---------------- fused prep + edge count (independent work overlapped in one launch) ----------------
#define CT_N (EE / 8)                                   // 80000 counting threads
#define CX_N (NN * 32)                                  // 640000 float4 casts
#define WP_N (128 * 1152 + 4 * 128 * 128 + 512)
__global__ __launch_bounds__(256) void prep_count(const int* __restrict__ ei,
                                                  const int* __restrict__ et,
                                                  int* __restrict__ cnt, int* __restrict__ rank,
                                                  const float* __restrict__ x,
                                                  const float* rw, const float* root,
                                                  const float* Wq, const float* Wk,
                                                  const float* Wv, const float* Ws,
                                                  const float* bq, const float* bk,
                                                  const float* bv, const float* bs,
                                                  u16* __restrict__ xb,
                                                  u16* wt1, u16* wt2, float* bcat) {
    int idx = blockIdx.x * 256 + threadIdx.x;
    if (idx < CT_N) {
#pragma unroll
        for (int j = 0; j < 8; j++) {
            int e = idx + j * CT_N;
            int dst = ei[EE + e];
            int r = et[e];
            rank[e] = atomicAdd(&cnt[dst * 8 + r], 1);
        }
        return;
    }
    idx -= CT_N;
    if (idx < CX_N) {
        float4 v = *(const float4*)(x + (size_t)idx * 4);
        uint2 o;
        o.x = packbf(v.x, v.y);
        o.y = packbf(v.z, v.w);
        *(uint2*)(xb + (size_t)idx * 4) = o;
        return;
    }
    idx -= CX_N;
    const int S1 = 128 * 1152, S2 = 4 * 128 * 128;
    if (idx < S1) {
        int o = idx / 1152, k = idx - o * 1152;
        float v = (k < 1024) ? rw[k * 128 + o] : root[(k - 1024) * 128 + o];
        wt1[idx] = f2bf(v);
    } else if (idx < S1 + S2) {
        int j = idx - S1;
        int y = j >> 14, rem = j & 16383, o = rem >> 7, i = rem & 127;
        const float* W = (y == 0) ? Wq : (y == 1) ? Wk : (y == 2) ? Wv : Ws;
        wt2[j] = f2bf(W[i * 128 + o]);
    } else if (idx < S1 + S2 + 512) {
        int j = idx - (S1 + S2);
        int y = j >> 7, c = j & 127;
        const float* b = (y == 0) ? bq : (y == 1) ? bk : (y == 2) ? bv : bs;
        bcat[j] = b[c];
    }
}

// ---------------- parallel scan (2 kernels) ----------------
__global__ __launch_bounds__(256) void scan_phase1(const int* __restrict__ cnt,
                                                   int* __restrict__ deg_pref,
                                                   int* __restrict__ blk_sums) {
    __shared__ int lds[256];
    int t = threadIdx.x;
    int n = blockIdx.x * 256 + t;
    int d = 0;
    if (n < NN) {
        int4 c0 = *(const int4*)(cnt + n * 8);
        int4 c1 = *(const int4*)(cnt + n * 8 + 4);
        d = c0.x + c0.y + c0.z + c0.w + c1.x + c1.y + c1.z + c1.w;
    }
    lds[t] = d;
    __syncthreads();
    for (int o = 1; o < 256; o <<= 1) {
        int v = (t >= o) ? lds[t - o] : 0;
        __syncthreads();
        lds[t] += v;
        __syncthreads();
    }
    if (n < NN) deg_pref[n] = lds[t];
    if (t == 255) blk_sums[blockIdx.x] = lds[255];
}

__global__ __launch_bounds__(256) void scan_phase3(const int* __restrict__ cnt,
                                                   const int* __restrict__ deg_pref,
                                                   const int* __restrict__ blk_sums,
                                                   int* __restrict__ row_off,
                                                   int* __restrict__ srt) {
    __shared__ int bs_lds[128];
    int t = threadIdx.x;
    if (t < 128) {
        int v = (t < SCAN_BLOCKS) ? blk_sums[t] : 0;
        bs_lds[t] = v;
    }
    __syncthreads();
    if (t < 128) {
        for (int o = 1; o < 128; o <<= 1) {
            int a = (t >= o) ? bs_lds[t - o] : 0;
            __syncthreads();
            bs_lds[t] += a;
            __syncthreads();
        }
    } else {
        for (int o = 1; o < 128; o <<= 1) {
            __syncthreads();
            __syncthreads();
        }
    }
    int blk_excl = (blockIdx.x > 0) ? bs_lds[blockIdx.x - 1] : 0;
    int n = blockIdx.x * 256 + t;
    if (n >= NN) return;
    int4 c0 = *(const int4*)(cnt + n * 8);
    int4 c1 = *(const int4*)(cnt + n * 8 + 4);
    int deg = c0.x + c0.y + c0.z + c0.w + c1.x + c1.y + c1.z + c1.w;
    int start = blk_excl + deg_pref[n] - deg;   // exclusive global prefix
    row_off[n] = start;
    int sub = start;
    int o[8];
    o[0] = sub; sub += c0.x;
    o[1] = sub; sub += c0.y;
    o[2] = sub; sub += c0.z;
    o[3] = sub; sub += c0.w;
    o[4] = sub; sub += c1.x;
    o[5] = sub; sub += c1.y;
    o[6] = sub; sub += c1.z;
    o[7] = sub; sub += c1.w;
    *(int4*)(srt + n * 8) = make_int4(o[0], o[1], o[2], o[3]);
    *(int4*)(srt + n * 8 + 4) = make_int4(o[4], o[5], o[6], o[7]);
    if (n == NN - 1) row_off[NN] = sub;
}

// atomic-free scatter, 8 edges/thread
__global__ void scatter_kernel(const int* __restrict__ ei, const int* __restrict__ et,
                               const int* __restrict__ srt, const int* __restrict__ rank,
                               int* __restrict__ es) {
    int base = blockIdx.x * 2048 + threadIdx.x;
#pragma unroll
    for (int j = 0; j < 8; j++) {
        int e = base + j * 256;
        if (e < EE) {
            int dst = ei[EE + e];
            int src = ei[e];
            int r = et[e];
            es[srt[dst * 8 + r] + rank[e]] = src;
        }
    }
}

// ---------------- fused RGCN-aggregate + GEMM, BM=16, B streamed global->registers ----------------
// The wt1/wt2 panels are identical across blocks and L2-resident: stream B fragments
// straight from global into MFMA operand registers (immediate-offset dwordx4 loads)
// instead of staging through LDS. Removes 13 staging phases + their barriers
// (28 -> 11 barriers), LDS 39.4 -> 8.7 KB, and B-load latency hides under the gather.
// As is double-buffered so each slot needs only ONE barrier.
__global__ __launch_bounds__(256) void gemm_rgcn_fused(const u16* __restrict__ xb,
                                                       const int* __restrict__ srt,
                                                       const int* __restrict__ cnt,
                                                       const int* __restrict__ es,
                                                       const u16* __restrict__ Bt1,
                                                       const float* __restrict__ bias1,
                                                       const u16* __restrict__ Wt2,
                                                       const float* __restrict__ bcat,
                                                       u16* __restrict__ Cq, u16* __restrict__ Ckv,
                                                       u16* __restrict__ Cs) {
    __shared__ u16 As[2][16 * 136];
    int tid = threadIdx.x;
    int w = tid >> 6;
    int lane = tid & 63;
    int quad = lane >> 4;
    int ml = lane & 15;
    int nq = w;              // 32-col quadrant per wave
    int block_m = blockIdx.x * 16;

    int node_l = tid >> 4;   // 0..15 : node within tile
    int th = tid & 15;       // 16 threads per node
    int db = th * 8;         // 8 dims per thread
    int gnode = block_m + node_l;

    // per-lane B base: row (nq*32+ml) of Bt1, k-offset quad*8; nt adds 16 rows, ks adds 32 k
    const u16* bp0 = Bt1 + (long)(nq * 32 + ml) * 1152 + quad * 8;

    f32x4 acc[2];
#pragma unroll
    for (int i = 0; i < 2; i++) acc[i] = (f32x4){0.f, 0.f, 0.f, 0.f};

    // ---- stage 1: h-tile = relu([agg_0..agg_7, x] @ wt1^T + b1) ----
#pragma unroll 1
    for (int slot = 0; slot < 9; slot++) {
        // issue B-fragment loads first (independent; latency hides under gather)
        short8 bf[4][2];
#pragma unroll
        for (int ks = 0; ks < 4; ks++)
#pragma unroll
            for (int nt = 0; nt < 2; nt++)
                bf[ks][nt] = *(const short8*)(bp0 + (long)nt * 16 * 1152 + slot * 128 + ks * 32);

        u16* dst = &As[slot & 1][node_l * 136 + db];
        if (slot < 8) {
            // gather-mean this relation's edges for my node, 8 dims
            int c = cnt[gnode * 8 + slot];
            int p0 = srt[gnode * 8 + slot];
            float a0 = 0.f, a1 = 0.f, a2 = 0.f, a3 = 0.f, a4 = 0.f, a5 = 0.f, a6 = 0.f, a7 = 0.f;
            int i = 0;
            for (; i + 2 <= c; i += 2) {
                int s0 = es[p0 + i], s1 = es[p0 + i + 1];
                uint4 wa = *(const uint4*)(xb + (long)s0 * 128 + db);
                uint4 wb = *(const uint4*)(xb + (long)s1 * 128 + db);
                a0 += lo16(wa.x) + lo16(wb.x);
                a1 += hi16(wa.x) + hi16(wb.x);
                a2 += lo16(wa.y) + lo16(wb.y);
                a3 += hi16(wa.y) + hi16(wb.y);
                a4 += lo16(wa.z) + lo16(wb.z);
                a5 += hi16(wa.z) + hi16(wb.z);
                a6 += lo16(wa.w) + lo16(wb.w);
                a7 += hi16(wa.w) + hi16(wb.w);
            }
            if (i < c) {
                int s0 = es[p0 + i];
                uint4 wa = *(const uint4*)(xb + (long)s0 * 128 + db);
                a0 += lo16(wa.x); a1 += hi16(wa.x); a2 += lo16(wa.y); a3 += hi16(wa.y);
                a4 += lo16(wa.z); a5 += hi16(wa.z); a6 += lo16(wa.w); a7 += hi16(wa.w);
            }
            float inv = 1.0f / (float)(c > 1 ? c : 1);
            uint4 o0 = make_uint4(packbf(a0 * inv, a1 * inv), packbf(a2 * inv, a3 * inv),
                                  packbf(a4 * inv, a5 * inv), packbf(a6 * inv, a7 * inv));
            *(uint4*)dst = o0;
        } else {
            // root chunk: A = xb rows directly
            short8 val = *(const short8*)(xb + (long)gnode * 128 + db);
            *(short8*)dst = val;
        }
        __syncthreads();
        const u16* ab = &As[slot & 1][0];
#pragma unroll
        for (int ks = 0; ks < 4; ks++) {
            short8 af = *(const short8*)(ab + ml * 136 + ks * 32 + quad * 8);
            acc[0] = __builtin_amdgcn_mfma_f32_16x16x32_bf16(af, bf[ks][0], acc[0], 0, 0, 0);
            acc[1] = __builtin_amdgcn_mfma_f32_16x16x32_bf16(af, bf[ks][1], acc[1], 0, 0, 0);
        }
    }
    __syncthreads();   // all slot-8 MFMA reads of As[0] done before h overwrites it

    // h-tile -> As[0]
#pragma unroll
    for (int nt = 0; nt < 2; nt++) {
        int col = nq * 32 + nt * 16 + ml;
        float bv = bias1[col];
#pragma unroll
        for (int i = 0; i < 4; i++) {
            int r = quad * 4 + i;
            As[0][r * 136 + col] = f2bf(fmaxf(acc[nt][i] + bv, 0.f));
        }
    }
    __syncthreads();

    // ---- stage 2: q / kv / skip projections; B from global, no barriers ----
#pragma unroll 1
    for (int y = 0; y < 4; y++) {
        const u16* wp = Wt2 + (long)y * 16384 + (long)(nq * 32 + ml) * 128 + quad * 8;
        short8 bf2[4][2];
#pragma unroll
        for (int ks = 0; ks < 4; ks++)
#pragma unroll
            for (int nt = 0; nt < 2; nt++)
                bf2[ks][nt] = *(const short8*)(wp + (long)nt * 16 * 128 + ks * 32);
        f32x4 acc2[2];
#pragma unroll
        for (int i = 0; i < 2; i++) acc2[i] = (f32x4){0.f, 0.f, 0.f, 0.f};
#pragma unroll
        for (int ks = 0; ks < 4; ks++) {
            short8 af = *(const short8*)(&As[0][ml * 136 + ks * 32 + quad * 8]);
            acc2[0] = __builtin_amdgcn_mfma_f32_16x16x32_bf16(af, bf2[ks][0], acc2[0], 0, 0, 0);
            acc2[1] = __builtin_amdgcn_mfma_f32_16x16x32_bf16(af, bf2[ks][1], acc2[1], 0, 0, 0);
        }
        u16* C;
        int ldc;
        if (y == 0) { C = Cq; ldc = 128; }
        else if (y == 1) { C = Ckv; ldc = 256; }
        else if (y == 2) { C = Ckv + 128; ldc = 256; }
        else { C = Cs; ldc = 128; }
#pragma unroll
        for (int nt = 0; nt < 2; nt++) {
            int col = nq * 32 + nt * 16 + ml;
            float bv = bcat[y * 128 + col];
#pragma unroll
            for (int i = 0; i < 4; i++) {
                int gr = block_m + quad * 4 + i;
                C[(long)gr * ldc + col] = f2bf(acc2[nt][i] + bv);
            }
        }
    }
}

// ---------------- attention: 16-lane/node, 8 nodes/block, direct-exp softmax, fused KV ----------------
__global__ __launch_bounds__(128) void attn_kernel(const u16* __restrict__ q,
                                                   const u16* __restrict__ kv,
                                                   const u16* __restrict__ skip,
                                                   const int* __restrict__ row_off,
                                                   const int* __restrict__ es,
                                                   float* __restrict__ out) {
    int node = blockIdx.x * 8 + (threadIdx.x >> 4);
    int lane = threadIdx.x & 15;     // 8 dims/lane
    if (node >= NN) return;
    int p0 = row_off[node], p1 = row_off[node + 1];
    uint4 qw = *(const uint4*)(q + (long)node * 128 + lane * 8);
    float q0 = lo16(qw.x), q1 = hi16(qw.x), q2 = lo16(qw.y), q3 = hi16(qw.y);
    float q4 = lo16(qw.z), q5 = hi16(qw.z), q6 = lo16(qw.w), q7 = hi16(qw.w);
    const float SC = 0.08838834764831845f;  // 1/sqrt(128)
    float l = 0.f;
    float a0 = 0.f, a1 = 0.f, a2 = 0.f, a3 = 0.f, a4 = 0.f, a5 = 0.f, a6 = 0.f, a7 = 0.f;
    int p = p0;
    for (; p + 4 <= p1; p += 4) {
        const u16* b0 = kv + (long)es[p] * 256 + lane * 8;
        const u16* b1 = kv + (long)es[p + 1] * 256 + lane * 8;
        const u16* b2 = kv + (long)es[p + 2] * 256 + lane * 8;
        const u16* b3 = kv + (long)es[p + 3] * 256 + lane * 8;
        uint4 k0 = *(const uint4*)b0;
        uint4 k1 = *(const uint4*)b1;
        uint4 k2 = *(const uint4*)b2;
        uint4 k3 = *(const uint4*)b3;
        uint4 v0 = *(const uint4*)(b0 + 128);
        uint4 v1 = *(const uint4*)(b1 + 128);
        uint4 v2 = *(const uint4*)(b2 + 128);
        uint4 v3 = *(const uint4*)(b3 + 128);
        float t0 = q0 * lo16(k0.x) + q1 * hi16(k0.x) + q2 * lo16(k0.y) + q3 * hi16(k0.y) +
                   q4 * lo16(k0.z) + q5 * hi16(k0.z) + q6 * lo16(k0.w) + q7 * hi16(k0.w);
        float t1 = q0 * lo16(k1.x) + q1 * hi16(k1.x) + q2 * lo16(k1.y) + q3 * hi16(k1.y) +
                   q4 * lo16(k1.z) + q5 * hi16(k1.z) + q6 * lo16(k1.w) + q7 * hi16(k1.w);
        float t2 = q0 * lo16(k2.x) + q1 * hi16(k2.x) + q2 * lo16(k2.y) + q3 * hi16(k2.y) +
                   q4 * lo16(k2.z) + q5 * hi16(k2.z) + q6 * lo16(k2.w) + q7 * hi16(k2.w);
        float t3 = q0 * lo16(k3.x) + q1 * hi16(k3.x) + q2 * lo16(k3.y) + q3 * hi16(k3.y) +
                   q4 * lo16(k3.z) + q5 * hi16(k3.z) + q6 * lo16(k3.w) + q7 * hi16(k3.w);
#pragma unroll
        for (int off = 8; off >= 1; off >>= 1) {
            t0 += __shfl_xor(t0, off, 16);
            t1 += __shfl_xor(t1, off, 16);
            t2 += __shfl_xor(t2, off, 16);
            t3 += __shfl_xor(t3, off, 16);
        }
        float w0 = __expf(fminf(t0 * SC, 70.f));
        float w1 = __expf(fminf(t1 * SC, 70.f));
        float w2 = __expf(fminf(t2 * SC, 70.f));
        float w3 = __expf(fminf(t3 * SC, 70.f));
        l += (w0 + w1) + (w2 + w3);
        a0 += w0 * lo16(v0.x) + w1 * lo16(v1.x) + w2 * lo16(v2.x) + w3 * lo16(v3.x);
        a1 += w0 * hi16(v0.x) + w1 * hi16(v1.x) + w2 * hi16(v2.x) + w3 * hi16(v3.x);
        a2 += w0 * lo16(v0.y) + w1 * lo16(v1.y) + w2 * lo16(v2.y) + w3 * lo16(v3.y);
        a3 += w0 * hi16(v0.y) + w1 * hi16(v1.y) + w2 * hi16(v2.y) + w3 * hi16(v3.y);
        a4 += w0 * lo16(v0.z) + w1 * lo16(v1.z) + w2 * lo16(v2.z) + w3 * lo16(v3.z);
        a5 += w0 * hi16(v0.z) + w1 * hi16(v1.z) + w2 * hi16(v2.z) + w3 * hi16(v3.z);
        a6 += w0 * lo16(v0.w) + w1 * lo16(v1.w) + w2 * lo16(v2.w) + w3 * lo16(v3.w);
        a7 += w0 * hi16(v0.w) + w1 * hi16(v1.w) + w2 * hi16(v2.w) + w3 * hi16(v3.w);
    }
    for (; p < p1; p++) {
        const u16* b = kv + (long)es[p] * 256 + lane * 8;
        uint4 kw = *(const uint4*)b;
        uint4 vw = *(const uint4*)(b + 128);
        float t = q0 * lo16(kw.x) + q1 * hi16(kw.x) + q2 * lo16(kw.y) + q3 * hi16(kw.y) +
                  q4 * lo16(kw.z) + q5 * hi16(kw.z) + q6 * lo16(kw.w) + q7 * hi16(kw.w);
#pragma unroll
        for (int off = 8; off >= 1; off >>= 1) t += __shfl_xor(t, off, 16);
        float w = __expf(fminf(t * SC, 70.f));
        l += w;
        a0 += w * lo16(vw.x);
        a1 += w * hi16(vw.x);
        a2 += w * lo16(vw.y);
        a3 += w * hi16(vw.y);
        a4 += w * lo16(vw.z);
        a5 += w * hi16(vw.z);
        a6 += w * lo16(vw.w);
        a7 += w * hi16(vw.w);
    }
    float invl = (l > 0.f) ? 1.0f / l : 0.f;
    uint4 sw = *(const uint4*)(skip + (long)node * 128 + lane * 8);
    float4 oa, ob;
    oa.x = fmaxf(a0 * invl + lo16(sw.x), 0.f);
    oa.y = fmaxf(a1 * invl + hi16(sw.x), 0.f);
    oa.z = fmaxf(a2 * invl + lo16(sw.y), 0.f);
    oa.w = fmaxf(a3 * invl + hi16(sw.y), 0.f);
    ob.x = fmaxf(a4 * invl + lo16(sw.z), 0.f);
    ob.y = fmaxf(a5 * invl + hi16(sw.z), 0.f);
    ob.z = fmaxf(a6 * invl + lo16(sw.w), 0.f);
    ob.w = fmaxf(a7 * invl + hi16(sw.w), 0.f);
    *(float4*)(out + (long)node * 128 + lane * 8) = oa;
    *(float4*)(out + (long)node * 128 + lane * 8 + 4) = ob;
}

extern "C" void kernel_launch(void* const* d_in, const int* in_sizes, int n_in,
                              void* d_out, int out_size, void* d_ws, size_t ws_size,
                              hipStream_t stream) {
    const float* x = (const float*)d_in[0];
    const int* ei = (const int*)d_in[1];
    const int* et = (const int*)d_in[2];
    const float* rw = (const float*)d_in[3];
    const float* root = (const float*)d_in[4];
    const float* rbias = (const float*)d_in[5];
    const float* Wq = (const float*)d_in[6];
    const float* bq = (const float*)d_in[7];
    const float* Wk = (const float*)d_in[8];
    const float* bk = (const float*)d_in[9];
    const float* Wv = (const float*)d_in[10];
    const float* bv = (const float*)d_in[11];
    const float* Ws = (const float*)d_in[12];
    const float* bs = (const float*)d_in[13];

    char* ws = (char*)d_ws;
    size_t off = 0;
    auto alloc = [&](size_t b) {
        size_t o = off;
        off = (off + b + 255) & ~(size_t)255;
        return o;
    };
    u16* qv = (u16*)(ws + alloc((size_t)NN * 128 * 2));
    u16* kv = (u16*)(ws + alloc((size_t)NN * 256 * 2));
    u16* skip = (u16*)(ws + alloc((size_t)NN * 128 * 2));
    u16* xb = (u16*)(ws + alloc((size_t)NN * 128 * 2));
    u16* wt1 = (u16*)(ws + alloc((size_t)128 * 1152 * 2));
    u16* wt2 = (u16*)(ws + alloc((size_t)4 * 128 * 128 * 2));
    float* bcat = (float*)(ws + alloc((size_t)512 * 4));
    int* cnt = (int*)(ws + alloc((size_t)NN * 8 * 4));
    int* row_off = (int*)(ws + alloc((size_t)(NN + 1) * 4));
    int* srt = (int*)(ws + alloc((size_t)NN * 8 * 4));
    int* deg_pref = (int*)(ws + alloc((size_t)NN * 4));
    int* blk_sums = (int*)(ws + alloc((size_t)128 * 4));
    int* rank = (int*)(ws + alloc((size_t)EE * 4));
    int* es = (int*)(ws + alloc((size_t)EE * 4));
    (void)ws_size;
    (void)in_sizes;
    (void)n_in;
    (void)out_size;

    hipMemsetAsync(cnt, 0, (size_t)NN * 8 * 4, stream);

    prep_count<<<(CT_N + CX_N + WP_N + 255) / 256, 256, 0, stream>>>(
        ei, et, cnt, rank, x, rw, root, Wq, Wk, Wv, Ws, bq, bk, bv, bs,
        xb, wt1, wt2, bcat);

    scan_phase1<<<SCAN_BLOCKS, 256, 0, stream>>>(cnt, deg_pref, blk_sums);
    scan_phase3<<<SCAN_BLOCKS, 256, 0, stream>>>(cnt, deg_pref, blk_sums, row_off, srt);
    scatter_kernel<<<(EE + 2047) / 2048, 256, 0, stream>>>(ei, et, srt, rank, es);

    gemm_rgcn_fused<<<NN / 16, 256, 0, stream>>>(xb, srt, cnt, es, wt1, rbias, wt2, bcat,
                                                 qv, kv, skip);

    attn_kernel<<<(NN + 7) / 8, 128, 0, stream>>>(qv, kv, skip, row_off, es, (float*)d_out);
}

// Round 6
// 258.296 us; speedup vs baseline: 1.0091x; 1.0091x over previous
//
#include <hip/hip_runtime.h>

typedef unsigned short u16;
typedef unsigned int u32;
typedef __attribute__((ext_vector_type(8))) short short8;
typedef __attribute__((ext_vector_type(4))) float f32x4;

#define NN 20000
#define EE 640000
#define SCAN_BLOCKS 80   // 80*256 = 20480 >= NN

__device__ inline u16 f2bf(float f) {
    u32 x = __float_as_uint(f);
    return (u16)((x + 0x7FFFu + ((x >> 16) & 1u)) >> 16);
}
__device__ inline float lo16(u32 w) { return __uint_as_float(w << 16); }
__device__ inline float hi16(u32 w) { return __uint_as_float(w & 0xFFFF0000u); }
__device__ inline u32 packbf(float a, float b) { return ((u32)f2bf(b) << 16) | (u32)f2bf(a); }

// ---------------- fused prep + edge count (independent work overlapped in one launch) ----------------
#define CT_N (EE / 8)                                   // 80000 counting threads
#define CX_N (NN * 32)                                  // 640000 float4 casts
#define WP_N (128 * 1152 + 4 * 128 * 128 + 512)
__global__ __launch_bounds__(256) void prep_count(const int* __restrict__ ei,
                                                  const int* __restrict__ et,
                                                  int* __restrict__ cnt, int* __restrict__ rank,
                                                  const float* __restrict__ x,
                                                  const float* rw, const float* root,
                                                  const float* Wq, const float* Wk,
                                                  const float* Wv, const float* Ws,
                                                  const float* bq, const float* bk,
                                                  const float* bv, const float* bs,
                                                  u16* __restrict__ xb,
                                                  u16* wt1, u16* wt2, float* bcat) {
    int idx = blockIdx.x * 256 + threadIdx.x;
    if (idx < CT_N) {
#pragma unroll
        for (int j = 0; j < 8; j++) {
            int e = idx + j * CT_N;
            int dst = ei[EE + e];
            int r = et[e];
            rank[e] = atomicAdd(&cnt[dst * 8 + r], 1);
        }
        return;
    }
    idx -= CT_N;
    if (idx < CX_N) {
        float4 v = *(const float4*)(x + (size_t)idx * 4);
        uint2 o;
        o.x = packbf(v.x, v.y);
        o.y = packbf(v.z, v.w);
        *(uint2*)(xb + (size_t)idx * 4) = o;
        return;
    }
    idx -= CX_N;
    const int S1 = 128 * 1152, S2 = 4 * 128 * 128;
    if (idx < S1) {
        int o = idx / 1152, k = idx - o * 1152;
        float v = (k < 1024) ? rw[k * 128 + o] : root[(k - 1024) * 128 + o];
        wt1[idx] = f2bf(v);
    } else if (idx < S1 + S2) {
        int j = idx - S1;
        int y = j >> 14, rem = j & 16383, o = rem >> 7, i = rem & 127;
        const float* W = (y == 0) ? Wq : (y == 1) ? Wk : (y == 2) ? Wv : Ws;
        wt2[j] = f2bf(W[i * 128 + o]);
    } else if (idx < S1 + S2 + 512) {
        int j = idx - (S1 + S2);
        int y = j >> 7, c = j & 127;
        const float* b = (y == 0) ? bq : (y == 1) ? bk : (y == 2) ? bv : bs;
        bcat[j] = b[c];
    }
}

// ---------------- parallel scan (2 kernels) ----------------
__global__ __launch_bounds__(256) void scan_phase1(const int* __restrict__ cnt,
                                                   int* __restrict__ deg_pref,
                                                   int* __restrict__ blk_sums) {
    __shared__ int lds[256];
    int t = threadIdx.x;
    int n = blockIdx.x * 256 + t;
    int d = 0;
    if (n < NN) {
        int4 c0 = *(const int4*)(cnt + n * 8);
        int4 c1 = *(const int4*)(cnt + n * 8 + 4);
        d = c0.x + c0.y + c0.z + c0.w + c1.x + c1.y + c1.z + c1.w;
    }
    lds[t] = d;
    __syncthreads();
    for (int o = 1; o < 256; o <<= 1) {
        int v = (t >= o) ? lds[t - o] : 0;
        __syncthreads();
        lds[t] += v;
        __syncthreads();
    }
    if (n < NN) deg_pref[n] = lds[t];
    if (t == 255) blk_sums[blockIdx.x] = lds[255];
}

__global__ __launch_bounds__(256) void scan_phase3(const int* __restrict__ cnt,
                                                   const int* __restrict__ deg_pref,
                                                   const int* __restrict__ blk_sums,
                                                   int* __restrict__ row_off,
                                                   int* __restrict__ srt) {
    __shared__ int bs_lds[128];
    int t = threadIdx.x;
    if (t < 128) {
        int v = (t < SCAN_BLOCKS) ? blk_sums[t] : 0;
        bs_lds[t] = v;
    }
    __syncthreads();
    if (t < 128) {
        for (int o = 1; o < 128; o <<= 1) {
            int a = (t >= o) ? bs_lds[t - o] : 0;
            __syncthreads();
            bs_lds[t] += a;
            __syncthreads();
        }
    } else {
        for (int o = 1; o < 128; o <<= 1) {
            __syncthreads();
            __syncthreads();
        }
    }
    int blk_excl = (blockIdx.x > 0) ? bs_lds[blockIdx.x - 1] : 0;
    int n = blockIdx.x * 256 + t;
    if (n >= NN) return;
    int4 c0 = *(const int4*)(cnt + n * 8);
    int4 c1 = *(const int4*)(cnt + n * 8 + 4);
    int deg = c0.x + c0.y + c0.z + c0.w + c1.x + c1.y + c1.z + c1.w;
    int start = blk_excl + deg_pref[n] - deg;   // exclusive global prefix
    row_off[n] = start;
    int sub = start;
    int o[8];
    o[0] = sub; sub += c0.x;
    o[1] = sub; sub += c0.y;
    o[2] = sub; sub += c0.z;
    o[3] = sub; sub += c0.w;
    o[4] = sub; sub += c1.x;
    o[5] = sub; sub += c1.y;
    o[6] = sub; sub += c1.z;
    o[7] = sub; sub += c1.w;
    *(int4*)(srt + n * 8) = make_int4(o[0], o[1], o[2], o[3]);
    *(int4*)(srt + n * 8 + 4) = make_int4(o[4], o[5], o[6], o[7]);
    if (n == NN - 1) row_off[NN] = sub;
}

// atomic-free scatter, 8 edges/thread
__global__ void scatter_kernel(const int* __restrict__ ei, const int* __restrict__ et,
                               const int* __restrict__ srt, const int* __restrict__ rank,
                               int* __restrict__ es) {
    int base = blockIdx.x * 2048 + threadIdx.x;
#pragma unroll
    for (int j = 0; j < 8; j++) {
        int e = base + j * 256;
        if (e < EE) {
            int dst = ei[EE + e];
            int src = ei[e];
            int r = et[e];
            es[srt[dst * 8 + r] + rank[e]] = src;
        }
    }
}

// ---------------- fused RGCN-aggregate + GEMM: ONE parallel gather phase ----------------
// 512 threads, BM=16: the block's 16 nodes x 8 slots = 128 (node,slot) pairs are
// gathered CONCURRENTLY (4 threads x 32 dims per pair) into a full 16x1152 A-panel
// in LDS, instead of 8-13 serial per-slot phases (R3/R4/R5: 62/84/92 us all tracked
// phase count). Then one barrier and 9 back-to-back MFMA slots with rolling B
// prefetch from L2. Barriers 11 -> 3. Layout: row stride 1224 u16, slot stride 136
// u16 (both /4 == 4 mod 32 -> bank-spread b128 access). Math identical to R3-R5.
__global__ __launch_bounds__(512) void gemm_rgcn_fused(const u16* __restrict__ xb,
                                                       const int* __restrict__ srt,
                                                       const int* __restrict__ cnt,
                                                       const int* __restrict__ es,
                                                       const u16* __restrict__ Bt1,
                                                       const float* __restrict__ bias1,
                                                       const u16* __restrict__ Wt2,
                                                       const float* __restrict__ bcat,
                                                       u16* __restrict__ Cq, u16* __restrict__ Ckv,
                                                       u16* __restrict__ Cs) {
    __shared__ u16 As[16 * 1224];
    int tid = threadIdx.x;
    int w = tid >> 6;        // 0..7 : wave -> 16 output cols
    int lane = tid & 63;
    int quad = lane >> 4;
    int ml = lane & 15;
    int block_m = blockIdx.x * 16;

    // per-thread B base: output col (w*16+ml), k-offset quad*8
    const u16* bp = Bt1 + (long)(w * 16 + ml) * 1152 + quad * 8;

    // prefetch slot-0 B fragments (latency hides under the gather)
    short8 bf[4], bfn[4];
#pragma unroll
    for (int ks = 0; ks < 4; ks++) bf[ks] = *(const short8*)(bp + ks * 32);

    // ---- single parallel gather: all 128 (node,slot) means at once ----
    {
        int pair = tid >> 2;     // 0..127
        int sub = tid & 3;       // 4 threads/pair, 32 dims each
        int node_l = pair >> 3;
        int slot = pair & 7;
        int gnode = block_m + node_l;
        int c = cnt[gnode * 8 + slot];
        int p0 = srt[gnode * 8 + slot];
        float a[32];
#pragma unroll
        for (int j = 0; j < 32; j++) a[j] = 0.f;
        const u16* xs = xb + sub * 32;
        int i = 0;
        for (; i + 2 <= c; i += 2) {
            const u16* r0 = xs + (long)es[p0 + i] * 128;
            const u16* r1 = xs + (long)es[p0 + i + 1] * 128;
            uint4 wa[4], wb[4];
#pragma unroll
            for (int k = 0; k < 4; k++) wa[k] = *(const uint4*)(r0 + k * 8);
#pragma unroll
            for (int k = 0; k < 4; k++) wb[k] = *(const uint4*)(r1 + k * 8);
#pragma unroll
            for (int k = 0; k < 4; k++) {
                a[k * 8 + 0] += lo16(wa[k].x) + lo16(wb[k].x);
                a[k * 8 + 1] += hi16(wa[k].x) + hi16(wb[k].x);
                a[k * 8 + 2] += lo16(wa[k].y) + lo16(wb[k].y);
                a[k * 8 + 3] += hi16(wa[k].y) + hi16(wb[k].y);
                a[k * 8 + 4] += lo16(wa[k].z) + lo16(wb[k].z);
                a[k * 8 + 5] += hi16(wa[k].z) + hi16(wb[k].z);
                a[k * 8 + 6] += lo16(wa[k].w) + lo16(wb[k].w);
                a[k * 8 + 7] += hi16(wa[k].w) + hi16(wb[k].w);
            }
        }
        if (i < c) {
            const u16* r0 = xs + (long)es[p0 + i] * 128;
#pragma unroll
            for (int k = 0; k < 4; k++) {
                uint4 wa = *(const uint4*)(r0 + k * 8);
                a[k * 8 + 0] += lo16(wa.x);
                a[k * 8 + 1] += hi16(wa.x);
                a[k * 8 + 2] += lo16(wa.y);
                a[k * 8 + 3] += hi16(wa.y);
                a[k * 8 + 4] += lo16(wa.z);
                a[k * 8 + 5] += hi16(wa.z);
                a[k * 8 + 6] += lo16(wa.w);
                a[k * 8 + 7] += hi16(wa.w);
            }
        }
        float inv = 1.0f / (float)(c > 1 ? c : 1);
        u16* dst = As + node_l * 1224 + slot * 136 + sub * 32;
#pragma unroll
        for (int k = 0; k < 4; k++) {
            uint4 o = make_uint4(packbf(a[k * 8 + 0] * inv, a[k * 8 + 1] * inv),
                                 packbf(a[k * 8 + 2] * inv, a[k * 8 + 3] * inv),
                                 packbf(a[k * 8 + 4] * inv, a[k * 8 + 5] * inv),
                                 packbf(a[k * 8 + 6] * inv, a[k * 8 + 7] * inv));
            *(uint4*)(dst + k * 8) = o;
        }
    }
    // root chunk: copy the tile's own xb rows (256 threads suffice)
    if (tid < 256) {
        int r = tid >> 4;
        int cb = (tid & 15) * 8;
        short8 val = *(const short8*)(xb + (long)(block_m + r) * 128 + cb);
        *(short8*)(As + r * 1224 + 8 * 136 + cb) = val;
    }
    __syncthreads();

    // ---- stage 1 MFMA: 9 slots back-to-back, rolling B prefetch ----
    f32x4 acc = (f32x4){0.f, 0.f, 0.f, 0.f};
#pragma unroll 1
    for (int slot = 0; slot < 9; slot++) {
        if (slot < 8) {
#pragma unroll
            for (int ks = 0; ks < 4; ks++)
                bfn[ks] = *(const short8*)(bp + (slot + 1) * 128 + ks * 32);
        }
#pragma unroll
        for (int ks = 0; ks < 4; ks++) {
            short8 af = *(const short8*)(As + ml * 1224 + slot * 136 + ks * 32 + quad * 8);
            acc = __builtin_amdgcn_mfma_f32_16x16x32_bf16(af, bf[ks], acc, 0, 0, 0);
        }
#pragma unroll
        for (int ks = 0; ks < 4; ks++) bf[ks] = bfn[ks];
    }

    // stage-2 y=0 B prefetch (issues before the h-write barriers)
    const u16* wp = Wt2 + (long)(w * 16 + ml) * 128 + quad * 8;
#pragma unroll
    for (int ks = 0; ks < 4; ks++) bfn[ks] = *(const short8*)(wp + ks * 32);

    __syncthreads();   // all waves done reading As before h overwrites slot-0 region
    {
        int col = w * 16 + ml;
        float bv = bias1[col];
#pragma unroll
        for (int i = 0; i < 4; i++)
            As[(quad * 4 + i) * 1224 + col] = f2bf(fmaxf(acc[i] + bv, 0.f));
    }
    __syncthreads();

    // ---- stage 2: q / kv / skip projections; no further barriers ----
#pragma unroll 1
    for (int y = 0; y < 4; y++) {
#pragma unroll
        for (int ks = 0; ks < 4; ks++) bf[ks] = bfn[ks];
        if (y < 3) {
#pragma unroll
            for (int ks = 0; ks < 4; ks++)
                bfn[ks] = *(const short8*)(wp + (long)(y + 1) * 16384 + ks * 32);
        }
        f32x4 acc2 = (f32x4){0.f, 0.f, 0.f, 0.f};
#pragma unroll
        for (int ks = 0; ks < 4; ks++) {
            short8 af = *(const short8*)(As + ml * 1224 + ks * 32 + quad * 8);
            acc2 = __builtin_amdgcn_mfma_f32_16x16x32_bf16(af, bf[ks], acc2, 0, 0, 0);
        }
        u16* C;
        int ldc;
        if (y == 0) { C = Cq; ldc = 128; }
        else if (y == 1) { C = Ckv; ldc = 256; }
        else if (y == 2) { C = Ckv + 128; ldc = 256; }
        else { C = Cs; ldc = 128; }
        int col = w * 16 + ml;
        float bv = bcat[y * 128 + col];
#pragma unroll
        for (int i = 0; i < 4; i++) {
            int gr = block_m + quad * 4 + i;
            C[(long)gr * ldc + col] = f2bf(acc2[i] + bv);
        }
    }
}

// ---------------- attention: 16-lane/node, 8 nodes/block, direct-exp softmax, fused KV ----------------
__global__ __launch_bounds__(128) void attn_kernel(const u16* __restrict__ q,
                                                   const u16* __restrict__ kv,
                                                   const u16* __restrict__ skip,
                                                   const int* __restrict__ row_off,
                                                   const int* __restrict__ es,
                                                   float* __restrict__ out) {
    int node = blockIdx.x * 8 + (threadIdx.x >> 4);
    int lane = threadIdx.x & 15;     // 8 dims/lane
    if (node >= NN) return;
    int p0 = row_off[node], p1 = row_off[node + 1];
    uint4 qw = *(const uint4*)(q + (long)node * 128 + lane * 8);
    float q0 = lo16(qw.x), q1 = hi16(qw.x), q2 = lo16(qw.y), q3 = hi16(qw.y);
    float q4 = lo16(qw.z), q5 = hi16(qw.z), q6 = lo16(qw.w), q7 = hi16(qw.w);
    const float SC = 0.08838834764831845f;  // 1/sqrt(128)
    float l = 0.f;
    float a0 = 0.f, a1 = 0.f, a2 = 0.f, a3 = 0.f, a4 = 0.f, a5 = 0.f, a6 = 0.f, a7 = 0.f;
    int p = p0;
    for (; p + 4 <= p1; p += 4) {
        const u16* b0 = kv + (long)es[p] * 256 + lane * 8;
        const u16* b1 = kv + (long)es[p + 1] * 256 + lane * 8;
        const u16* b2 = kv + (long)es[p + 2] * 256 + lane * 8;
        const u16* b3 = kv + (long)es[p + 3] * 256 + lane * 8;
        uint4 k0 = *(const uint4*)b0;
        uint4 k1 = *(const uint4*)b1;
        uint4 k2 = *(const uint4*)b2;
        uint4 k3 = *(const uint4*)b3;
        uint4 v0 = *(const uint4*)(b0 + 128);
        uint4 v1 = *(const uint4*)(b1 + 128);
        uint4 v2 = *(const uint4*)(b2 + 128);
        uint4 v3 = *(const uint4*)(b3 + 128);
        float t0 = q0 * lo16(k0.x) + q1 * hi16(k0.x) + q2 * lo16(k0.y) + q3 * hi16(k0.y) +
                   q4 * lo16(k0.z) + q5 * hi16(k0.z) + q6 * lo16(k0.w) + q7 * hi16(k0.w);
        float t1 = q0 * lo16(k1.x) + q1 * hi16(k1.x) + q2 * lo16(k1.y) + q3 * hi16(k1.y) +
                   q4 * lo16(k1.z) + q5 * hi16(k1.z) + q6 * lo16(k1.w) + q7 * hi16(k1.w);
        float t2 = q0 * lo16(k2.x) + q1 * hi16(k2.x) + q2 * lo16(k2.y) + q3 * hi16(k2.y) +
                   q4 * lo16(k2.z) + q5 * hi16(k2.z) + q6 * lo16(k2.w) + q7 * hi16(k2.w);
        float t3 = q0 * lo16(k3.x) + q1 * hi16(k3.x) + q2 * lo16(k3.y) + q3 * hi16(k3.y) +
                   q4 * lo16(k3.z) + q5 * hi16(k3.z) + q6 * lo16(k3.w) + q7 * hi16(k3.w);
#pragma unroll
        for (int off = 8; off >= 1; off >>= 1) {
            t0 += __shfl_xor(t0, off, 16);
            t1 += __shfl_xor(t1, off, 16);
            t2 += __shfl_xor(t2, off, 16);
            t3 += __shfl_xor(t3, off, 16);
        }
        float w0 = __expf(fminf(t0 * SC, 70.f));
        float w1 = __expf(fminf(t1 * SC, 70.f));
        float w2 = __expf(fminf(t2 * SC, 70.f));
        float w3 = __expf(fminf(t3 * SC, 70.f));
        l += (w0 + w1) + (w2 + w3);
        a0 += w0 * lo16(v0.x) + w1 * lo16(v1.x) + w2 * lo16(v2.x) + w3 * lo16(v3.x);
        a1 += w0 * hi16(v0.x) + w1 * hi16(v1.x) + w2 * hi16(v2.x) + w3 * hi16(v3.x);
        a2 += w0 * lo16(v0.y) + w1 * lo16(v1.y) + w2 * lo16(v2.y) + w3 * lo16(v3.y);
        a3 += w0 * hi16(v0.y) + w1 * hi16(v1.y) + w2 * hi16(v2.y) + w3 * hi16(v3.y);
        a4 += w0 * lo16(v0.z) + w1 * lo16(v1.z) + w2 * lo16(v2.z) + w3 * lo16(v3.z);
        a5 += w0 * hi16(v0.z) + w1 * hi16(v1.z) + w2 * hi16(v2.z) + w3 * hi16(v3.z);
        a6 += w0 * lo16(v0.w) + w1 * lo16(v1.w) + w2 * lo16(v2.w) + w3 * lo16(v3.w);
        a7 += w0 * hi16(v0.w) + w1 * hi16(v1.w) + w2 * hi16(v2.w) + w3 * hi16(v3.w);
    }
    for (; p < p1; p++) {
        const u16* b = kv + (long)es[p] * 256 + lane * 8;
        uint4 kw = *(const uint4*)b;
        uint4 vw = *(const uint4*)(b + 128);
        float t = q0 * lo16(kw.x) + q1 * hi16(kw.x) + q2 * lo16(kw.y) + q3 * hi16(kw.y) +
                  q4 * lo16(kw.z) + q5 * hi16(kw.z) + q6 * lo16(kw.w) + q7 * hi16(kw.w);
#pragma unroll
        for (int off = 8; off >= 1; off >>= 1) t += __shfl_xor(t, off, 16);
        float w = __expf(fminf(t * SC, 70.f));
        l += w;
        a0 += w * lo16(vw.x);
        a1 += w * hi16(vw.x);
        a2 += w * lo16(vw.y);
        a3 += w * hi16(vw.y);
        a4 += w * lo16(vw.z);
        a5 += w * hi16(vw.z);
        a6 += w * lo16(vw.w);
        a7 += w * hi16(vw.w);
    }
    float invl = (l > 0.f) ? 1.0f / l : 0.f;
    uint4 sw = *(const uint4*)(skip + (long)node * 128 + lane * 8);
    float4 oa, ob;
    oa.x = fmaxf(a0 * invl + lo16(sw.x), 0.f);
    oa.y = fmaxf(a1 * invl + hi16(sw.x), 0.f);
    oa.z = fmaxf(a2 * invl + lo16(sw.y), 0.f);
    oa.w = fmaxf(a3 * invl + hi16(sw.y), 0.f);
    ob.x = fmaxf(a4 * invl + lo16(sw.z), 0.f);
    ob.y = fmaxf(a5 * invl + hi16(sw.z), 0.f);
    ob.z = fmaxf(a6 * invl + lo16(sw.w), 0.f);
    ob.w = fmaxf(a7 * invl + hi16(sw.w), 0.f);
    *(float4*)(out + (long)node * 128 + lane * 8) = oa;
    *(float4*)(out + (long)node * 128 + lane * 8 + 4) = ob;
}

extern "C" void kernel_launch(void* const* d_in, const int* in_sizes, int n_in,
                              void* d_out, int out_size, void* d_ws, size_t ws_size,
                              hipStream_t stream) {
    const float* x = (const float*)d_in[0];
    const int* ei = (const int*)d_in[1];
    const int* et = (const int*)d_in[2];
    const float* rw = (const float*)d_in[3];
    const float* root = (const float*)d_in[4];
    const float* rbias = (const float*)d_in[5];
    const float* Wq = (const float*)d_in[6];
    const float* bq = (const float*)d_in[7];
    const float* Wk = (const float*)d_in[8];
    const float* bk = (const float*)d_in[9];
    const float* Wv = (const float*)d_in[10];
    const float* bv = (const float*)d_in[11];
    const float* Ws = (const float*)d_in[12];
    const float* bs = (const float*)d_in[13];

    char* ws = (char*)d_ws;
    size_t off = 0;
    auto alloc = [&](size_t b) {
        size_t o = off;
        off = (off + b + 255) & ~(size_t)255;
        return o;
    };
    u16* qv = (u16*)(ws + alloc((size_t)NN * 128 * 2));
    u16* kv = (u16*)(ws + alloc((size_t)NN * 256 * 2));
    u16* skip = (u16*)(ws + alloc((size_t)NN * 128 * 2));
    u16* xb = (u16*)(ws + alloc((size_t)NN * 128 * 2));
    u16* wt1 = (u16*)(ws + alloc((size_t)128 * 1152 * 2));
    u16* wt2 = (u16*)(ws + alloc((size_t)4 * 128 * 128 * 2));
    float* bcat = (float*)(ws + alloc((size_t)512 * 4));
    int* cnt = (int*)(ws + alloc((size_t)NN * 8 * 4));
    int* row_off = (int*)(ws + alloc((size_t)(NN + 1) * 4));
    int* srt = (int*)(ws + alloc((size_t)NN * 8 * 4));
    int* deg_pref = (int*)(ws + alloc((size_t)NN * 4));
    int* blk_sums = (int*)(ws + alloc((size_t)128 * 4));
    int* rank = (int*)(ws + alloc((size_t)EE * 4));
    int* es = (int*)(ws + alloc((size_t)EE * 4));
    (void)ws_size;
    (void)in_sizes;
    (void)n_in;
    (void)out_size;

    hipMemsetAsync(cnt, 0, (size_t)NN * 8 * 4, stream);

    prep_count<<<(CT_N + CX_N + WP_N + 255) / 256, 256, 0, stream>>>(
        ei, et, cnt, rank, x, rw, root, Wq, Wk, Wv, Ws, bq, bk, bv, bs,
        xb, wt1, wt2, bcat);

    scan_phase1<<<SCAN_BLOCKS, 256, 0, stream>>>(cnt, deg_pref, blk_sums);
    scan_phase3<<<SCAN_BLOCKS, 256, 0, stream>>>(cnt, deg_pref, blk_sums, row_off, srt);
    scatter_kernel<<<(EE + 2047) / 2048, 256, 0, stream>>>(ei, et, srt, rank, es);

    gemm_rgcn_fused<<<NN / 16, 512, 0, stream>>>(xb, srt, cnt, es, wt1, rbias, wt2, bcat,
                                                 qv, kv, skip);

    attn_kernel<<<(NN + 7) / 8, 128, 0, stream>>>(qv, kv, skip, row_off, es, (float*)d_out);
}

// Round 7
// 230.872 us; speedup vs baseline: 1.1289x; 1.1188x over previous
//
#include <hip/hip_runtime.h>

typedef unsigned short u16;
typedef unsigned int u32;
typedef __attribute__((ext_vector_type(8))) short short8;
typedef __attribute__((ext_vector_type(4))) float f32x4;

#define NN 20000
#define EE 640000
#define SCAN_BLOCKS 80   // 80*256 = 20480 >= NN

__device__ inline u16 f2bf(float f) {
    u32 x = __float_as_uint(f);
    return (u16)((x + 0x7FFFu + ((x >> 16) & 1u)) >> 16);
}
__device__ inline float lo16(u32 w) { return __uint_as_float(w << 16); }
__device__ inline float hi16(u32 w) { return __uint_as_float(w & 0xFFFF0000u); }
__device__ inline u32 packbf(float a, float b) { return ((u32)f2bf(b) << 16) | (u32)f2bf(a); }

// ---------------- fused prep + edge count (independent work overlapped in one launch) ----------------
#define CT_N (EE / 8)                                   // 80000 counting threads
#define CX_N (NN * 32)                                  // 640000 float4 casts
#define WP_N (128 * 1152 + 4 * 128 * 128 + 512)
__global__ __launch_bounds__(256) void prep_count(const int* __restrict__ ei,
                                                  const int* __restrict__ et,
                                                  int* __restrict__ cnt, int* __restrict__ rank,
                                                  const float* __restrict__ x,
                                                  const float* rw, const float* root,
                                                  const float* Wq, const float* Wk,
                                                  const float* Wv, const float* Ws,
                                                  const float* bq, const float* bk,
                                                  const float* bv, const float* bs,
                                                  u16* __restrict__ xb, u16* __restrict__ pre,
                                                  u16* wt1, u16* wt2, float* bcat) {
    int idx = blockIdx.x * 256 + threadIdx.x;
    if (idx < CT_N) {
#pragma unroll
        for (int j = 0; j < 8; j++) {
            int e = idx + j * CT_N;
            int dst = ei[EE + e];
            int r = et[e];
            rank[e] = atomicAdd(&cnt[dst * 8 + r], 1);
        }
        return;
    }
    idx -= CT_N;
    if (idx < CX_N) {
        float4 v = *(const float4*)(x + (size_t)idx * 4);
        uint2 o;
        o.x = packbf(v.x, v.y);
        o.y = packbf(v.z, v.w);
        *(uint2*)(xb + (size_t)idx * 4) = o;
        int node = idx >> 5;
        int d = (idx & 31) * 4;
        *(uint2*)(pre + (long)node * 1152 + 1024 + d) = o;   // rgcn slot-8 fused
        return;
    }
    idx -= CX_N;
    const int S1 = 128 * 1152, S2 = 4 * 128 * 128;
    if (idx < S1) {
        int o = idx / 1152, k = idx - o * 1152;
        float v = (k < 1024) ? rw[k * 128 + o] : root[(k - 1024) * 128 + o];
        wt1[idx] = f2bf(v);
    } else if (idx < S1 + S2) {
        int j = idx - S1;
        int y = j >> 14, rem = j & 16383, o = rem >> 7, i = rem & 127;
        const float* W = (y == 0) ? Wq : (y == 1) ? Wk : (y == 2) ? Wv : Ws;
        wt2[j] = f2bf(W[i * 128 + o]);
    } else if (idx < S1 + S2 + 512) {
        int j = idx - (S1 + S2);
        int y = j >> 7, c = j & 127;
        const float* b = (y == 0) ? bq : (y == 1) ? bk : (y == 2) ? bv : bs;
        bcat[j] = b[c];
    }
}

// ---------------- parallel scan (2 kernels) ----------------
__global__ __launch_bounds__(256) void scan_phase1(const int* __restrict__ cnt,
                                                   int* __restrict__ deg_pref,
                                                   int* __restrict__ blk_sums) {
    __shared__ int lds[256];
    int t = threadIdx.x;
    int n = blockIdx.x * 256 + t;
    int d = 0;
    if (n < NN) {
        int4 c0 = *(const int4*)(cnt + n * 8);
        int4 c1 = *(const int4*)(cnt + n * 8 + 4);
        d = c0.x + c0.y + c0.z + c0.w + c1.x + c1.y + c1.z + c1.w;
    }
    lds[t] = d;
    __syncthreads();
    for (int o = 1; o < 256; o <<= 1) {
        int v = (t >= o) ? lds[t - o] : 0;
        __syncthreads();
        lds[t] += v;
        __syncthreads();
    }
    if (n < NN) deg_pref[n] = lds[t];
    if (t == 255) blk_sums[blockIdx.x] = lds[255];
}

__global__ __launch_bounds__(256) void scan_phase3(const int* __restrict__ cnt,
                                                   const int* __restrict__ deg_pref,
                                                   const int* __restrict__ blk_sums,
                                                   int* __restrict__ row_off,
                                                   int* __restrict__ srt) {
    __shared__ int bs_lds[128];
    int t = threadIdx.x;
    if (t < 128) {
        int v = (t < SCAN_BLOCKS) ? blk_sums[t] : 0;
        bs_lds[t] = v;
    }
    __syncthreads();
    if (t < 128) {
        for (int o = 1; o < 128; o <<= 1) {
            int a = (t >= o) ? bs_lds[t - o] : 0;
            __syncthreads();
            bs_lds[t] += a;
            __syncthreads();
        }
    } else {
        for (int o = 1; o < 128; o <<= 1) {
            __syncthreads();
            __syncthreads();
        }
    }
    int blk_excl = (blockIdx.x > 0) ? bs_lds[blockIdx.x - 1] : 0;
    int n = blockIdx.x * 256 + t;
    if (n >= NN) return;
    int4 c0 = *(const int4*)(cnt + n * 8);
    int4 c1 = *(const int4*)(cnt + n * 8 + 4);
    int deg = c0.x + c0.y + c0.z + c0.w + c1.x + c1.y + c1.z + c1.w;
    int start = blk_excl + deg_pref[n] - deg;   // exclusive global prefix
    row_off[n] = start;
    int sub = start;
    int o[8];
    o[0] = sub; sub += c0.x;
    o[1] = sub; sub += c0.y;
    o[2] = sub; sub += c0.z;
    o[3] = sub; sub += c0.w;
    o[4] = sub; sub += c1.x;
    o[5] = sub; sub += c1.y;
    o[6] = sub; sub += c1.z;
    o[7] = sub; sub += c1.w;
    *(int4*)(srt + n * 8) = make_int4(o[0], o[1], o[2], o[3]);
    *(int4*)(srt + n * 8 + 4) = make_int4(o[4], o[5], o[6], o[7]);
    if (n == NN - 1) row_off[NN] = sub;
}

// atomic-free scatter, 8 edges/thread
__global__ void scatter_kernel(const int* __restrict__ ei, const int* __restrict__ et,
                               const int* __restrict__ srt, const int* __restrict__ rank,
                               int* __restrict__ es) {
    int base = blockIdx.x * 2048 + threadIdx.x;
#pragma unroll
    for (int j = 0; j < 8; j++) {
        int e = base + j * 256;
        if (e < EE) {
            int dst = ei[EE + e];
            int src = ei[e];
            int r = et[e];
            es[srt[dst * 8 + r] + rank[e]] = src;
        }
    }
}

// ---------------- RGCN pre-aggregation: 8-lane group per (node,relation), 16 dims/lane ----------------
// 8->16 dims/lane doubles independent uint4 loads in flight per lane (8 per 4-edge
// batch) against the L3-latency-bound gather (per-XCD xb replication, FETCH ~8x5MB).
// Per-dim summation order identical to the 16-lane version -> bit-identical output.
__global__ __launch_bounds__(256) void rgcn_agg(const u16* __restrict__ xb,
                                                const int* __restrict__ srt,
                                                const int* __restrict__ cnt,
                                                const int* __restrict__ es,
                                                u16* __restrict__ pre) {
    int gid = blockIdx.x * 32 + (threadIdx.x >> 3);
    int lane = threadIdx.x & 7;      // 16 dims/lane
    if (gid >= NN * 8) return;
    int node = gid >> 3;
    int slot = gid & 7;
    int c = cnt[node * 8 + slot];
    int p0 = srt[node * 8 + slot];
    float inv = 1.0f / (float)(c > 1 ? c : 1);
    int db = lane * 16;
    float a0 = 0.f, a1 = 0.f, a2 = 0.f, a3 = 0.f, a4 = 0.f, a5 = 0.f, a6 = 0.f, a7 = 0.f;
    float b0 = 0.f, b1 = 0.f, b2 = 0.f, b3 = 0.f, b4 = 0.f, b5 = 0.f, b6 = 0.f, b7 = 0.f;
    int i = 0;
    for (; i + 4 <= c; i += 4) {
        int s0 = es[p0 + i], s1 = es[p0 + i + 1], s2 = es[p0 + i + 2], s3 = es[p0 + i + 3];
        const u16* r0 = xb + (long)s0 * 128 + db;
        const u16* r1 = xb + (long)s1 * 128 + db;
        const u16* r2 = xb + (long)s2 * 128 + db;
        const u16* r3 = xb + (long)s3 * 128 + db;
        uint4 w0 = *(const uint4*)r0;
        uint4 w1 = *(const uint4*)r1;
        uint4 w2 = *(const uint4*)r2;
        uint4 w3 = *(const uint4*)r3;
        uint4 v0 = *(const uint4*)(r0 + 8);
        uint4 v1 = *(const uint4*)(r1 + 8);
        uint4 v2 = *(const uint4*)(r2 + 8);
        uint4 v3 = *(const uint4*)(r3 + 8);
        a0 += (lo16(w0.x) + lo16(w1.x)) + (lo16(w2.x) + lo16(w3.x));
        a1 += (hi16(w0.x) + hi16(w1.x)) + (hi16(w2.x) + hi16(w3.x));
        a2 += (lo16(w0.y) + lo16(w1.y)) + (lo16(w2.y) + lo16(w3.y));
        a3 += (hi16(w0.y) + hi16(w1.y)) + (hi16(w2.y) + hi16(w3.y));
        a4 += (lo16(w0.z) + lo16(w1.z)) + (lo16(w2.z) + lo16(w3.z));
        a5 += (hi16(w0.z) + hi16(w1.z)) + (hi16(w2.z) + hi16(w3.z));
        a6 += (lo16(w0.w) + lo16(w1.w)) + (lo16(w2.w) + lo16(w3.w));
        a7 += (hi16(w0.w) + hi16(w1.w)) + (hi16(w2.w) + hi16(w3.w));
        b0 += (lo16(v0.x) + lo16(v1.x)) + (lo16(v2.x) + lo16(v3.x));
        b1 += (hi16(v0.x) + hi16(v1.x)) + (hi16(v2.x) + hi16(v3.x));
        b2 += (lo16(v0.y) + lo16(v1.y)) + (lo16(v2.y) + lo16(v3.y));
        b3 += (hi16(v0.y) + hi16(v1.y)) + (hi16(v2.y) + hi16(v3.y));
        b4 += (lo16(v0.z) + lo16(v1.z)) + (lo16(v2.z) + lo16(v3.z));
        b5 += (hi16(v0.z) + hi16(v1.z)) + (hi16(v2.z) + hi16(v3.z));
        b6 += (lo16(v0.w) + lo16(v1.w)) + (lo16(v2.w) + lo16(v3.w));
        b7 += (hi16(v0.w) + hi16(v1.w)) + (hi16(v2.w) + hi16(v3.w));
    }
    for (; i < c; i++) {
        const u16* r = xb + (long)es[p0 + i] * 128 + db;
        uint4 w = *(const uint4*)r;
        uint4 v = *(const uint4*)(r + 8);
        a0 += lo16(w.x); a1 += hi16(w.x); a2 += lo16(w.y); a3 += hi16(w.y);
        a4 += lo16(w.z); a5 += hi16(w.z); a6 += lo16(w.w); a7 += hi16(w.w);
        b0 += lo16(v.x); b1 += hi16(v.x); b2 += lo16(v.y); b3 += hi16(v.y);
        b4 += lo16(v.z); b5 += hi16(v.z); b6 += lo16(v.w); b7 += hi16(v.w);
    }
    uint4 ow0, ow1;
    ow0.x = packbf(a0 * inv, a1 * inv);
    ow0.y = packbf(a2 * inv, a3 * inv);
    ow0.z = packbf(a4 * inv, a5 * inv);
    ow0.w = packbf(a6 * inv, a7 * inv);
    ow1.x = packbf(b0 * inv, b1 * inv);
    ow1.y = packbf(b2 * inv, b3 * inv);
    ow1.z = packbf(b4 * inv, b5 * inv);
    ow1.w = packbf(b6 * inv, b7 * inv);
    u16* dst = pre + (long)node * 1152 + slot * 128 + db;
    *(uint4*)dst = ow0;
    *(uint4*)(dst + 8) = ow1;
}

// ---------------- fused GEMM: h=relu(pre@W1+b1) kept in LDS, then q/kv/skip = h@Wy+by ----------------
__global__ __launch_bounds__(256) void gemm_fused(const u16* __restrict__ A,
                                                  const u16* __restrict__ Bt1,
                                                  const float* __restrict__ bias1,
                                                  const u16* __restrict__ Wt2,
                                                  const float* __restrict__ bcat,
                                                  u16* __restrict__ Cq, u16* __restrict__ Ckv,
                                                  u16* __restrict__ Cs) {
    __shared__ u16 As[32 * 136];
    __shared__ u16 Bs[128 * 136];
    int tid = threadIdx.x;
    int w = tid >> 6;
    int lane = tid & 63;
    int quad = lane >> 4;
    int ml = lane & 15;
    int mt = w & 1;
    int nq = w >> 1;
    int block_m = blockIdx.x * 32;

    f32x4 acc[4];
#pragma unroll
    for (int i = 0; i < 4; i++) acc[i] = (f32x4){0.f, 0.f, 0.f, 0.f};

    int rbase = tid >> 4;
    int cb = (tid & 15) * 8;

    // ---- stage 1: h-tile = relu(pre-tile @ wt1^T + b1) ----
    for (int kb = 0; kb < 1152; kb += 128) {
#pragma unroll
        for (int rep = 0; rep < 2; rep++) {
            int r = rbase + rep * 16;
            short8 val = *(const short8*)(A + (long)(block_m + r) * 1152 + kb + cb);
            *(short8*)(As + r * 136 + cb) = val;
        }
#pragma unroll
        for (int rep = 0; rep < 8; rep++) {
            int r = rbase + rep * 16;
            short8 val = *(const short8*)(Bt1 + (long)r * 1152 + kb + cb);
            *(short8*)(Bs + r * 136 + cb) = val;
        }
        __syncthreads();
#pragma unroll
        for (int ks = 0; ks < 4; ks++) {
            short8 af = *(const short8*)(As + (mt * 16 + ml) * 136 + ks * 32 + quad * 8);
#pragma unroll
            for (int nt = 0; nt < 4; nt++) {
                short8 bfr = *(const short8*)(Bs + (nq * 64 + nt * 16 + ml) * 136 + ks * 32 + quad * 8);
                acc[nt] = __builtin_amdgcn_mfma_f32_16x16x32_bf16(af, bfr, acc[nt], 0, 0, 0);
            }
        }
        __syncthreads();
    }
#pragma unroll
    for (int nt = 0; nt < 4; nt++) {
        int col = nq * 64 + nt * 16 + ml;
        float bv = bias1[col];
#pragma unroll
        for (int i = 0; i < 4; i++) {
            int r = mt * 16 + quad * 4 + i;
            As[r * 136 + col] = f2bf(fmaxf(acc[nt][i] + bv, 0.f));
        }
    }
    __syncthreads();

    // ---- stage 2: q / kv / skip projections from the LDS h-tile ----
#pragma unroll 1
    for (int y = 0; y < 4; y++) {
#pragma unroll
        for (int rep = 0; rep < 8; rep++) {
            int r = rbase + rep * 16;
            short8 val = *(const short8*)(Wt2 + (long)y * 16384 + (long)r * 128 + cb);
            *(short8*)(Bs + r * 136 + cb) = val;
        }
        __syncthreads();
        f32x4 acc2[4];
#pragma unroll
        for (int i = 0; i < 4; i++) acc2[i] = (f32x4){0.f, 0.f, 0.f, 0.f};
#pragma unroll
        for (int ks = 0; ks < 4; ks++) {
            short8 af = *(const short8*)(As + (mt * 16 + ml) * 136 + ks * 32 + quad * 8);
#pragma unroll
            for (int nt = 0; nt < 4; nt++) {
                short8 bfr = *(const short8*)(Bs + (nq * 64 + nt * 16 + ml) * 136 + ks * 32 + quad * 8);
                acc2[nt] = __builtin_amdgcn_mfma_f32_16x16x32_bf16(af, bfr, acc2[nt], 0, 0, 0);
            }
        }
        u16* C;
        int ldc;
        if (y == 0) { C = Cq; ldc = 128; }
        else if (y == 1) { C = Ckv; ldc = 256; }
        else if (y == 2) { C = Ckv + 128; ldc = 256; }
        else { C = Cs; ldc = 128; }
#pragma unroll
        for (int nt = 0; nt < 4; nt++) {
            int col = nq * 64 + nt * 16 + ml;
            float bv = bcat[y * 128 + col];
#pragma unroll
            for (int i = 0; i < 4; i++) {
                int gr = block_m + mt * 16 + quad * 4 + i;
                C[(long)gr * ldc + col] = f2bf(acc2[nt][i] + bv);
            }
        }
        __syncthreads();
    }
}

// ---------------- attention: 16-lane/node, 8 nodes/block, direct-exp softmax, fused KV ----------------
__global__ __launch_bounds__(128) void attn_kernel(const u16* __restrict__ q,
                                                   const u16* __restrict__ kv,
                                                   const u16* __restrict__ skip,
                                                   const int* __restrict__ row_off,
                                                   const int* __restrict__ es,
                                                   float* __restrict__ out) {
    int node = blockIdx.x * 8 + (threadIdx.x >> 4);
    int lane = threadIdx.x & 15;     // 8 dims/lane
    if (node >= NN) return;
    int p0 = row_off[node], p1 = row_off[node + 1];
    uint4 qw = *(const uint4*)(q + (long)node * 128 + lane * 8);
    float q0 = lo16(qw.x), q1 = hi16(qw.x), q2 = lo16(qw.y), q3 = hi16(qw.y);
    float q4 = lo16(qw.z), q5 = hi16(qw.z), q6 = lo16(qw.w), q7 = hi16(qw.w);
    const float SC = 0.08838834764831845f;  // 1/sqrt(128)
    float l = 0.f;
    float a0 = 0.f, a1 = 0.f, a2 = 0.f, a3 = 0.f, a4 = 0.f, a5 = 0.f, a6 = 0.f, a7 = 0.f;
    int p = p0;
    for (; p + 4 <= p1; p += 4) {
        const u16* b0 = kv + (long)es[p] * 256 + lane * 8;
        const u16* b1 = kv + (long)es[p + 1] * 256 + lane * 8;
        const u16* b2 = kv + (long)es[p + 2] * 256 + lane * 8;
        const u16* b3 = kv + (long)es[p + 3] * 256 + lane * 8;
        uint4 k0 = *(const uint4*)b0;
        uint4 k1 = *(const uint4*)b1;
        uint4 k2 = *(const uint4*)b2;
        uint4 k3 = *(const uint4*)b3;
        uint4 v0 = *(const uint4*)(b0 + 128);
        uint4 v1 = *(const uint4*)(b1 + 128);
        uint4 v2 = *(const uint4*)(b2 + 128);
        uint4 v3 = *(const uint4*)(b3 + 128);
        float t0 = q0 * lo16(k0.x) + q1 * hi16(k0.x) + q2 * lo16(k0.y) + q3 * hi16(k0.y) +
                   q4 * lo16(k0.z) + q5 * hi16(k0.z) + q6 * lo16(k0.w) + q7 * hi16(k0.w);
        float t1 = q0 * lo16(k1.x) + q1 * hi16(k1.x) + q2 * lo16(k1.y) + q3 * hi16(k1.y) +
                   q4 * lo16(k1.z) + q5 * hi16(k1.z) + q6 * lo16(k1.w) + q7 * hi16(k1.w);
        float t2 = q0 * lo16(k2.x) + q1 * hi16(k2.x) + q2 * lo16(k2.y) + q3 * hi16(k2.y) +
                   q4 * lo16(k2.z) + q5 * hi16(k2.z) + q6 * lo16(k2.w) + q7 * hi16(k2.w);
        float t3 = q0 * lo16(k3.x) + q1 * hi16(k3.x) + q2 * lo16(k3.y) + q3 * hi16(k3.y) +
                   q4 * lo16(k3.z) + q5 * hi16(k3.z) + q6 * lo16(k3.w) + q7 * hi16(k3.w);
#pragma unroll
        for (int off = 8; off >= 1; off >>= 1) {
            t0 += __shfl_xor(t0, off, 16);
            t1 += __shfl_xor(t1, off, 16);
            t2 += __shfl_xor(t2, off, 16);
            t3 += __shfl_xor(t3, off, 16);
        }
        float w0 = __expf(fminf(t0 * SC, 70.f));
        float w1 = __expf(fminf(t1 * SC, 70.f));
        float w2 = __expf(fminf(t2 * SC, 70.f));
        float w3 = __expf(fminf(t3 * SC, 70.f));
        l += (w0 + w1) + (w2 + w3);
        a0 += w0 * lo16(v0.x) + w1 * lo16(v1.x) + w2 * lo16(v2.x) + w3 * lo16(v3.x);
        a1 += w0 * hi16(v0.x) + w1 * hi16(v1.x) + w2 * hi16(v2.x) + w3 * hi16(v3.x);
        a2 += w0 * lo16(v0.y) + w1 * lo16(v1.y) + w2 * lo16(v2.y) + w3 * lo16(v3.y);
        a3 += w0 * hi16(v0.y) + w1 * hi16(v1.y) + w2 * hi16(v2.y) + w3 * hi16(v3.y);
        a4 += w0 * lo16(v0.z) + w1 * lo16(v1.z) + w2 * lo16(v2.z) + w3 * lo16(v3.z);
        a5 += w0 * hi16(v0.z) + w1 * hi16(v1.z) + w2 * hi16(v2.z) + w3 * hi16(v3.z);
        a6 += w0 * lo16(v0.w) + w1 * lo16(v1.w) + w2 * lo16(v2.w) + w3 * lo16(v3.w);
        a7 += w0 * hi16(v0.w) + w1 * hi16(v1.w) + w2 * hi16(v2.w) + w3 * hi16(v3.w);
    }
    for (; p < p1; p++) {
        const u16* b = kv + (long)es[p] * 256 + lane * 8;
        uint4 kw = *(const uint4*)b;
        uint4 vw = *(const uint4*)(b + 128);
        float t = q0 * lo16(kw.x) + q1 * hi16(kw.x) + q2 * lo16(kw.y) + q3 * hi16(kw.y) +
                  q4 * lo16(kw.z) + q5 * hi16(kw.z) + q6 * lo16(kw.w) + q7 * hi16(kw.w);
#pragma unroll
        for (int off = 8; off >= 1; off >>= 1) t += __shfl_xor(t, off, 16);
        float w = __expf(fminf(t * SC, 70.f));
        l += w;
        a0 += w * lo16(vw.x);
        a1 += w * hi16(vw.x);
        a2 += w * lo16(vw.y);
        a3 += w * hi16(vw.y);
        a4 += w * lo16(vw.z);
        a5 += w * hi16(vw.z);
        a6 += w * lo16(vw.w);
        a7 += w * hi16(vw.w);
    }
    float invl = (l > 0.f) ? 1.0f / l : 0.f;
    uint4 sw = *(const uint4*)(skip + (long)node * 128 + lane * 8);
    float4 oa, ob;
    oa.x = fmaxf(a0 * invl + lo16(sw.x), 0.f);
    oa.y = fmaxf(a1 * invl + hi16(sw.x), 0.f);
    oa.z = fmaxf(a2 * invl + lo16(sw.y), 0.f);
    oa.w = fmaxf(a3 * invl + hi16(sw.y), 0.f);
    ob.x = fmaxf(a4 * invl + lo16(sw.z), 0.f);
    ob.y = fmaxf(a5 * invl + hi16(sw.z), 0.f);
    ob.z = fmaxf(a6 * invl + lo16(sw.w), 0.f);
    ob.w = fmaxf(a7 * invl + hi16(sw.w), 0.f);
    *(float4*)(out + (long)node * 128 + lane * 8) = oa;
    *(float4*)(out + (long)node * 128 + lane * 8 + 4) = ob;
}

extern "C" void kernel_launch(void* const* d_in, const int* in_sizes, int n_in,
                              void* d_out, int out_size, void* d_ws, size_t ws_size,
                              hipStream_t stream) {
    const float* x = (const float*)d_in[0];
    const int* ei = (const int*)d_in[1];
    const int* et = (const int*)d_in[2];
    const float* rw = (const float*)d_in[3];
    const float* root = (const float*)d_in[4];
    const float* rbias = (const float*)d_in[5];
    const float* Wq = (const float*)d_in[6];
    const float* bq = (const float*)d_in[7];
    const float* Wk = (const float*)d_in[8];
    const float* bk = (const float*)d_in[9];
    const float* Wv = (const float*)d_in[10];
    const float* bv = (const float*)d_in[11];
    const float* Ws = (const float*)d_in[12];
    const float* bs = (const float*)d_in[13];

    char* ws = (char*)d_ws;
    size_t off = 0;
    auto alloc = [&](size_t b) {
        size_t o = off;
        off = (off + b + 255) & ~(size_t)255;
        return o;
    };
    u16* pre = (u16*)(ws + alloc((size_t)NN * 1152 * 2));
    u16* qv = (u16*)(ws + alloc((size_t)NN * 128 * 2));
    u16* kv = (u16*)(ws + alloc((size_t)NN * 256 * 2));
    u16* skip = (u16*)(ws + alloc((size_t)NN * 128 * 2));
    u16* xb = (u16*)(ws + alloc((size_t)NN * 128 * 2));
    u16* wt1 = (u16*)(ws + alloc((size_t)128 * 1152 * 2));
    u16* wt2 = (u16*)(ws + alloc((size_t)4 * 128 * 128 * 2));
    float* bcat = (float*)(ws + alloc((size_t)512 * 4));
    int* cnt = (int*)(ws + alloc((size_t)NN * 8 * 4));
    int* row_off = (int*)(ws + alloc((size_t)(NN + 1) * 4));
    int* srt = (int*)(ws + alloc((size_t)NN * 8 * 4));
    int* deg_pref = (int*)(ws + alloc((size_t)NN * 4));
    int* blk_sums = (int*)(ws + alloc((size_t)128 * 4));
    int* rank = (int*)(ws + alloc((size_t)EE * 4));
    int* es = (int*)(ws + alloc((size_t)EE * 4));
    (void)ws_size;
    (void)in_sizes;
    (void)n_in;
    (void)out_size;

    hipMemsetAsync(cnt, 0, (size_t)NN * 8 * 4, stream);

    prep_count<<<(CT_N + CX_N + WP_N + 255) / 256, 256, 0, stream>>>(
        ei, et, cnt, rank, x, rw, root, Wq, Wk, Wv, Ws, bq, bk, bv, bs,
        xb, pre, wt1, wt2, bcat);

    scan_phase1<<<SCAN_BLOCKS, 256, 0, stream>>>(cnt, deg_pref, blk_sums);
    scan_phase3<<<SCAN_BLOCKS, 256, 0, stream>>>(cnt, deg_pref, blk_sums, row_off, srt);
    scatter_kernel<<<(EE + 2047) / 2048, 256, 0, stream>>>(ei, et, srt, rank, es);

    rgcn_agg<<<(NN * 8 + 31) / 32, 256, 0, stream>>>(xb, srt, cnt, es, pre);

    gemm_fused<<<NN / 32, 256, 0, stream>>>(pre, wt1, rbias, wt2, bcat, qv, kv, skip);

    attn_kernel<<<(NN + 7) / 8, 128, 0, stream>>>(qv, kv, skip, row_off, es, (float*)d_out);
}